// Round 3
// baseline (126.663 us; speedup 1.0000x reference)
//
#include <hip/hip_runtime.h>

#define HW 4096
#define CCH 256
#define MOFF 432
#define PTOT 32768
#define PDIM 66
#define PIMG (PDIM*PDIM)      // 4356 padded pixels per image

typedef unsigned short u16;
typedef __attribute__((ext_vector_type(8))) short short8;
typedef __attribute__((ext_vector_type(8))) unsigned short u16x8;
typedef __attribute__((ext_vector_type(4))) float f32x4;

__device__ __forceinline__ u16 f2b(float f){
  unsigned int u = __float_as_uint(f);
  unsigned int rounding = 0x7FFFu + ((u >> 16) & 1u);
  return (u16)((u + rounding) >> 16);
}
__device__ __forceinline__ float b2f(u16 s){
  return __uint_as_float(((unsigned int)s) << 16);
}

// ---------------------------------------------------------------------------
// k_cvtw: weights fp32 -> bf16 (woff zero-padded to 448 rows), BN fold.
// ---------------------------------------------------------------------------
__global__ __launch_bounds__(256) void k_cvtw(const float* __restrict__ w1,
    const float* __restrict__ woff, const float* __restrict__ w2,
    const float* __restrict__ gamma, const float* __restrict__ beta,
    const float* __restrict__ mean, const float* __restrict__ var,
    u16* __restrict__ wb1, u16* __restrict__ wboff, u16* __restrict__ wb2,
    float* __restrict__ bnA, float* __restrict__ bnB){
  int r = blockIdx.x, t = threadIdx.x;
  if (r < 256) wb1[r*256 + t] = f2b(w1[r*256 + t]);
  else if (r < 704){ int o = r - 256; wboff[o*256 + t] = (o < MOFF) ? f2b(woff[o*256 + t]) : (u16)0; }
  else if (r < 960){ int o = r - 704; wb2[o*256 + t] = f2b(w2[o*256 + t]); }
  else if (t < 256){
    float sc = gamma[t] * rsqrtf(var[t] + 1e-5f);
    bnA[t] = sc;
    bnB[t] = beta[t] - mean[t] * sc;
  }
}

// ---------------------------------------------------------------------------
// k_zb: zero the 260 border pixels per image of padded h1p. grid 260 x 256.
// Each block: 8 border pixels x 256 ch. thread -> one u16x8 segment.
// ---------------------------------------------------------------------------
__global__ __launch_bounds__(256) void k_zb(u16* __restrict__ h1p){
  int idx = blockIdx.x * 8 + (threadIdx.x >> 5);   // border index 0..2079
  int seg = threadIdx.x & 31;
  int img = idx / 260, n = idx % 260;
  int row, col;
  if (n < 66){ row = 0; col = n; }
  else if (n < 132){ row = 65; col = n - 66; }
  else if (n < 196){ row = n - 132 + 1; col = 0; }
  else { row = n - 196 + 1; col = 65; }
  u16x8 z = {};
  *reinterpret_cast<u16x8*>(&h1p[((size_t)img * PIMG + row * PDIM + col) * 256 + seg * 8]) = z;
}

// ---------------------------------------------------------------------------
// k_gemm: C[M=32768][N] = A * B^T, bf16 MFMA 16x16x32, tile 128 x BN, BK=32.
// AMODE 0: A dense bf16 [p][256]
// AMODE 1: A = x fp32 NCHW, fused transpose in staging
// AMODE 2: A = padded h1p bf16
// PADC: store C into padded h1p layout.
// SILU: y = acc*bias + bnB; out = y*sigmoid(y), fp32 NCHW.
// ---------------------------------------------------------------------------
template<int BN, bool GUARD, bool SILU, int AMODE, bool PADC>
__global__ __launch_bounds__(256) void k_gemm(const void* __restrict__ Asrc,
    const u16* __restrict__ Bw, const float* __restrict__ bias,
    const float* __restrict__ bnB, void* __restrict__ Cout, int ldc, int NL){
  constexpr int WN = BN / 2;
  constexpr int MF = 4;
  constexpr int NF = WN / 16;
  constexpr int BOFF = 128 * 40;
  constexpr int STG = (128 + BN) * 40;
  constexpr int CMAT = 128 * (BN + 8);
  constexpr int SM = SILU ? STG : (STG > CMAT ? STG : CMAT);
  __shared__ __align__(16) u16 smem[SM];

  const int t = threadIdx.x;
  const int tm = blockIdx.x * 128;
  const int tn = blockIdx.y * BN;
  const int lane = t & 63;
  const int wid = t >> 6;
  const int wr = wid >> 1, wc = wid & 1;

  f32x4 acc[MF][NF] = {};

  for (int kc = 0; kc < 256; kc += 32){
    if constexpr (AMODE == 1){
      const float* xs = (const float*)Asrc;
      const int bb = tm >> 12, ploc = tm & 4095;
      #pragma unroll
      for (int r = 0; r < 4; ++r){
        int flat = t + r * 256;
        int c_l = flat >> 5, p4 = (flat & 31) * 4;
        float4 xv = *reinterpret_cast<const float4*>(
          &xs[((size_t)(bb * 256 + kc + c_l)) * HW + ploc + p4]);
        smem[(p4 + 0) * 40 + c_l] = f2b(xv.x);
        smem[(p4 + 1) * 40 + c_l] = f2b(xv.y);
        smem[(p4 + 2) * 40 + c_l] = f2b(xv.z);
        smem[(p4 + 3) * 40 + c_l] = f2b(xv.w);
      }
    } else if constexpr (AMODE == 2){
      const u16* Ap = (const u16*)Asrc;
      #pragma unroll
      for (int i = 0; i < 2; ++i){
        int v = t + i * 256;
        int row = v >> 2, cq = v & 3;
        int p = tm + row;
        int bb = p >> 12, ii = (p >> 6) & 63, jj = p & 63;
        size_t base = ((size_t)(bb * PIMG) + (ii + 1) * PDIM + jj + 1) * 256;
        *reinterpret_cast<u16x8*>(&smem[row * 40 + cq * 8]) =
          *reinterpret_cast<const u16x8*>(&Ap[base + kc + cq * 8]);
      }
    } else {
      const u16* Ap = (const u16*)Asrc;
      #pragma unroll
      for (int i = 0; i < 2; ++i){
        int v = t + i * 256;
        int row = v >> 2, cq = v & 3;
        *reinterpret_cast<u16x8*>(&smem[row * 40 + cq * 8]) =
          *reinterpret_cast<const u16x8*>(&Ap[(size_t)(tm + row) * 256 + kc + cq * 8]);
      }
    }
    constexpr int BV = BN * 4 / 256;
    #pragma unroll
    for (int i = 0; i < BV; ++i){
      int v = t + i * 256;
      int row = v >> 2, cq = v & 3;
      *reinterpret_cast<u16x8*>(&smem[BOFF + row * 40 + cq * 8]) =
        *reinterpret_cast<const u16x8*>(&Bw[(size_t)(tn + row) * 256 + kc + cq * 8]);
    }
    __syncthreads();
    short8 af[MF], bf[NF];
    #pragma unroll
    for (int m = 0; m < MF; ++m)
      af[m] = *reinterpret_cast<const short8*>(
        &smem[(wr * 64 + m * 16 + (lane & 15)) * 40 + (lane >> 4) * 8]);
    #pragma unroll
    for (int n = 0; n < NF; ++n)
      bf[n] = *reinterpret_cast<const short8*>(
        &smem[BOFF + (wc * WN + n * 16 + (lane & 15)) * 40 + (lane >> 4) * 8]);
    #pragma unroll
    for (int m = 0; m < MF; ++m)
      #pragma unroll
      for (int n = 0; n < NF; ++n)
        acc[m][n] = __builtin_amdgcn_mfma_f32_16x16x32_bf16(af[m], bf[n], acc[m][n], 0, 0, 0);
    __syncthreads();
  }

  if constexpr (SILU){
    const int bimg = tm >> 12;
    const int ploc = tm & 4095;
    float* outp = (float*)Cout;
    #pragma unroll
    for (int n = 0; n < NF; ++n){
      int o = tn + wc * WN + n * 16 + (lane & 15);
      float sA = bias[o], sB = bnB[o];
      #pragma unroll
      for (int m = 0; m < MF; ++m){
        int prow = wr * 64 + m * 16 + ((lane >> 4) << 2);
        f32x4 st;
        #pragma unroll
        for (int j = 0; j < 4; ++j){
          float y = acc[m][n][j] * sA + sB;
          st[j] = y / (1.f + expf(-y));
        }
        *reinterpret_cast<f32x4*>(&outp[((size_t)(bimg * 256 + o)) * HW + ploc + prow]) = st;
      }
    }
  } else {
    constexpr int CP = BN + 8;
    u16* C_l = smem;
    #pragma unroll
    for (int n = 0; n < NF; ++n){
      int col = wc * WN + n * 16 + (lane & 15);
      int o = tn + col;
      float bi = (!GUARD || o < NL) ? bias[o] : 0.f;
      #pragma unroll
      for (int m = 0; m < MF; ++m){
        int r0 = wr * 64 + m * 16 + ((lane >> 4) << 2);
        #pragma unroll
        for (int j = 0; j < 4; ++j)
          C_l[(r0 + j) * CP + col] = f2b(acc[m][n][j] + bi);
      }
    }
    __syncthreads();
    constexpr int SEG = BN / 8;
    constexpr int RPP = 256 / SEG;
    u16* Co = (u16*)Cout;
    #pragma unroll
    for (int pass = 0; pass < 128 / RPP; ++pass){
      int row = pass * RPP + t / SEG;
      int sg = t % SEG;
      int oc = tn + sg * 8;
      if constexpr (PADC){
        int p = tm + row;
        int bb = p >> 12, ii = (p >> 6) & 63, jj = p & 63;
        size_t dst = ((size_t)(bb * PIMG) + (ii + 1) * PDIM + jj + 1) * 256 + oc;
        *reinterpret_cast<u16x8*>(&Co[dst]) =
          *reinterpret_cast<const u16x8*>(&C_l[row * CP + sg * 8]);
      } else {
        if (!GUARD || oc + 8 <= NL)
          *reinterpret_cast<u16x8*>(&Co[(size_t)(tm + row) * ldc + oc]) =
            *reinterpret_cast<const u16x8*>(&C_l[row * CP + sg * 8]);
      }
    }
  }
}

// ---------------------------------------------------------------------------
// k_sample: 16 px/block, thread = (pixel, group) owns all 16 channels.
// Padded h1p: every OOB corner clamps into a zero border cell -> branchless.
// ---------------------------------------------------------------------------
__global__ __launch_bounds__(256) void k_sample(const u16* __restrict__ h1p,
    const u16* __restrict__ om, u16* __restrict__ ydcn){
  __shared__ float oms[16 * MOFF];
  const int t = threadIdx.x;
  const int pblk = blockIdx.x * 16;
  {
    const u16* src = om + (size_t)pblk * MOFF;
    #pragma unroll
    for (int i = 0; i < 4; ++i){
      int idx = t + i * 256;
      if (idx < 864){
        u16x8 v = *reinterpret_cast<const u16x8*>(&src[idx * 8]);
        float4 lo, hi;
        lo.x = b2f(v[0]); lo.y = b2f(v[1]); lo.z = b2f(v[2]); lo.w = b2f(v[3]);
        hi.x = b2f(v[4]); hi.y = b2f(v[5]); hi.z = b2f(v[6]); hi.w = b2f(v[7]);
        *reinterpret_cast<float4*>(&oms[idx * 8]) = lo;
        *reinterpret_cast<float4*>(&oms[idx * 8 + 4]) = hi;
      }
    }
  }
  __syncthreads();
  const int pix = t >> 4, g = t & 15;
  const int p = pblk + pix;
  const int b = p >> 12, hw = p & 4095;
  const int ic = hw >> 6, jc = hw & 63;
  const u16* vb = h1p + ((size_t)b * PIMG + PDIM + 1) * 256 + g * 16;
  const float* ob = &oms[pix * MOFF + g * 27];
  const float fi = (float)ic, fj = (float)jc;
  float acc[16] = {};
  #pragma unroll
  for (int k = 0; k < 9; ++k){
    float oh = ob[2 * k], ow = ob[2 * k + 1], m = ob[18 + k];
    float ph = fi + (float)(k / 3 - 1) + oh;
    float pw = fj + (float)(k % 3 - 1) + ow;
    float h0f = floorf(ph), w0f = floorf(pw);
    float ah = ph - h0f, aw = pw - w0f;
    int h0 = (int)h0f, w0 = (int)w0f;
    int h0c = min(max(h0, -1), 64), h1c = min(max(h0 + 1, -1), 64);
    int w0c = min(max(w0, -1), 64), w1c = min(max(w0 + 1, -1), 64);
    int r0 = h0c * PDIM, r1 = h1c * PDIM;
    float mh1 = m * ah, mh0 = m - mh1;
    float c01 = mh0 * aw, c00 = mh0 - c01;
    float c11 = mh1 * aw, c10 = mh1 - c11;
    u16x8 a00l = *reinterpret_cast<const u16x8*>(&vb[(r0 + w0c) * 256]);
    u16x8 a00h = *reinterpret_cast<const u16x8*>(&vb[(r0 + w0c) * 256 + 8]);
    u16x8 a01l = *reinterpret_cast<const u16x8*>(&vb[(r0 + w1c) * 256]);
    u16x8 a01h = *reinterpret_cast<const u16x8*>(&vb[(r0 + w1c) * 256 + 8]);
    u16x8 a10l = *reinterpret_cast<const u16x8*>(&vb[(r1 + w0c) * 256]);
    u16x8 a10h = *reinterpret_cast<const u16x8*>(&vb[(r1 + w0c) * 256 + 8]);
    u16x8 a11l = *reinterpret_cast<const u16x8*>(&vb[(r1 + w1c) * 256]);
    u16x8 a11h = *reinterpret_cast<const u16x8*>(&vb[(r1 + w1c) * 256 + 8]);
    #pragma unroll
    for (int j = 0; j < 8; ++j){
      acc[j]     += c00 * b2f(a00l[j]) + c01 * b2f(a01l[j])
                  + c10 * b2f(a10l[j]) + c11 * b2f(a11l[j]);
      acc[8 + j] += c00 * b2f(a00h[j]) + c01 * b2f(a01h[j])
                  + c10 * b2f(a10h[j]) + c11 * b2f(a11h[j]);
    }
  }
  u16x8 o0, o1;
  #pragma unroll
  for (int j = 0; j < 8; ++j){ o0[j] = f2b(acc[j]); o1[j] = f2b(acc[8 + j]); }
  u16* dst = ydcn + (size_t)p * 256 + g * 16;
  *reinterpret_cast<u16x8*>(dst) = o0;
  *reinterpret_cast<u16x8*>(&dst[8]) = o1;
}

extern "C" void kernel_launch(void* const* d_in, const int* in_sizes, int n_in,
                              void* d_out, int out_size, void* d_ws, size_t ws_size,
                              hipStream_t stream) {
  const float* x     = (const float*)d_in[0];
  const float* w1    = (const float*)d_in[1];
  const float* b1    = (const float*)d_in[2];
  const float* woff  = (const float*)d_in[3];
  const float* boff  = (const float*)d_in[4];
  const float* w2    = (const float*)d_in[5];
  const float* gamma = (const float*)d_in[6];
  const float* beta  = (const float*)d_in[7];
  const float* mean  = (const float*)d_in[8];
  const float* var   = (const float*)d_in[9];
  float* out = (float*)d_out;
  (void)in_sizes; (void)n_in; (void)out_size; (void)ws_size;

  u16* h1p   = (u16*)d_ws;                                // 8*4356*256 u16 = 17.8 MB
  u16* om    = h1p + (size_t)8 * PIMG * 256;              // 32768*432
  u16* ydcn  = om + (size_t)PTOT * MOFF;                  // 32768*256
  u16* wb1   = ydcn + (size_t)PTOT * CCH;                 // 256*256
  u16* wboff = wb1 + 256 * 256;                           // 448*256
  u16* wb2   = wboff + 448 * 256;                         // 256*256
  float* bnA = (float*)(wb2 + 256 * 256);
  float* bnB = bnA + 256;

  dim3 blk(256);
  k_zb  <<<dim3(260), blk, 0, stream>>>(h1p);
  k_cvtw<<<dim3(961), blk, 0, stream>>>(w1, woff, w2, gamma, beta, mean, var,
                                        wb1, wboff, wb2, bnA, bnB);
  k_gemm<128, false, false, 1, true><<<dim3(PTOT / 128, 2), blk, 0, stream>>>(
      (const void*)x, wb1, b1, nullptr, (void*)h1p, 0, 256);
  k_gemm<64, true, false, 2, false><<<dim3(PTOT / 128, 7), blk, 0, stream>>>(
      (const void*)h1p, wboff, boff, nullptr, (void*)om, MOFF, MOFF);
  k_sample<<<dim3(PTOT / 16), blk, 0, stream>>>(h1p, om, ydcn);
  k_gemm<128, false, true, 0, false><<<dim3(PTOT / 128, 2), blk, 0, stream>>>(
      (const void*)ydcn, wb2, bnA, bnB, (void*)out, 0, 256);
}

// Round 4
// 109.161 us; speedup vs baseline: 1.1603x; 1.1603x over previous
//
#include <hip/hip_runtime.h>

#define HW 4096
#define CCH 256
#define MOFF 432
#define PTOT 32768
#define PDIM 68
#define PIMG (PDIM*PDIM)      // 4624 padded pixels per image (2-wide zero border)

typedef unsigned short u16;
typedef __attribute__((ext_vector_type(8))) short short8;
typedef __attribute__((ext_vector_type(8))) unsigned short u16x8;
typedef __attribute__((ext_vector_type(4))) unsigned short u16x4;
typedef __attribute__((ext_vector_type(4))) float f32x4;

__device__ __forceinline__ u16 f2b(float f){
  unsigned int u = __float_as_uint(f);
  unsigned int rounding = 0x7FFFu + ((u >> 16) & 1u);
  return (u16)((u + rounding) >> 16);
}
__device__ __forceinline__ float b2f(u16 s){
  return __uint_as_float(((unsigned int)s) << 16);
}

// ---------------------------------------------------------------------------
// k_cvtw: weights fp32 -> bf16, BN fold, AND zero h1p's 2-wide border.
// grid 1489 x 256. Blocks 0..960: weights/BN. Blocks 961..1488: border zero
// (8 border pixels per block, 32 threads x 16B each).
// ---------------------------------------------------------------------------
__global__ __launch_bounds__(256) void k_cvtw(const float* __restrict__ w1,
    const float* __restrict__ woff, const float* __restrict__ w2,
    const float* __restrict__ gamma, const float* __restrict__ beta,
    const float* __restrict__ mean, const float* __restrict__ var,
    u16* __restrict__ wb1, u16* __restrict__ wboff, u16* __restrict__ wb2,
    float* __restrict__ bnA, float* __restrict__ bnB, u16* __restrict__ h1p){
  int r = blockIdx.x, t = threadIdx.x;
  if (r < 256) wb1[r*256 + t] = f2b(w1[r*256 + t]);
  else if (r < 704){ int o = r - 256; wboff[o*256 + t] = (o < MOFF) ? f2b(woff[o*256 + t]) : (u16)0; }
  else if (r < 960){ int o = r - 704; wb2[o*256 + t] = f2b(w2[o*256 + t]); }
  else if (r == 960){
    if (t < 256){
      float sc = gamma[t] * rsqrtf(var[t] + 1e-5f);
      bnA[t] = sc;
      bnB[t] = beta[t] - mean[t] * sc;
    }
  } else {
    // border zero: 528 border px per image (rows 0,1,66,67 full; cols 0,1,66,67 of rows 2..65)
    int n = (r - 961) * 8 + (t >> 5);   // 0..4223
    int seg = t & 31;
    int img = n / 528, m = n % 528;
    int row, col;
    if (m < 136){ row = m / 68; col = m % 68; }
    else if (m < 272){ int mm = m - 136; row = 66 + mm / 68; col = mm % 68; }
    else { int mm = m - 272; row = 2 + (mm >> 2); int c4 = mm & 3; col = (c4 & 1) + 66 * (c4 >> 1); }
    u16x8 z = {};
    *reinterpret_cast<u16x8*>(&h1p[((size_t)img * PIMG + row * PDIM + col) * 256 + seg * 8]) = z;
  }
}

// ---------------------------------------------------------------------------
// k_xt: x fp32 NCHW -> xT bf16 [p][c]. grid (64, 4, 8) x 256. Conflict-free
// 64x64 f32 LDS tile (pad 65).
// ---------------------------------------------------------------------------
__global__ __launch_bounds__(256) void k_xt(const float* __restrict__ x,
    u16* __restrict__ xT){
  __shared__ float tile[64][65];
  const int pb = blockIdx.x * 64, cb = blockIdx.y * 64, b = blockIdx.z;
  const int t = threadIdx.x;
  const float* src = x + ((size_t)(b * CCH + cb)) * HW + pb;
  #pragma unroll
  for (int pass = 0; pass < 4; ++pass){
    int c_l = pass * 16 + (t >> 4);
    int pq = (t & 15) * 4;
    float4 v = *reinterpret_cast<const float4*>(&src[(size_t)c_l * HW + pq]);
    tile[pq + 0][c_l] = v.x; tile[pq + 1][c_l] = v.y;
    tile[pq + 2][c_l] = v.z; tile[pq + 3][c_l] = v.w;
  }
  __syncthreads();
  #pragma unroll
  for (int pass = 0; pass < 4; ++pass){
    int p_l = pass * 16 + (t >> 4);
    int cq = (t & 15) * 4;
    u16x4 o4;
    #pragma unroll
    for (int j = 0; j < 4; ++j) o4[j] = f2b(tile[p_l][cq + j]);
    *reinterpret_cast<u16x4*>(&xT[((size_t)b * HW + pb + p_l) * CCH + cb + cq]) = o4;
  }
}

// ---------------------------------------------------------------------------
// k_gemm: C[M=32768][N] = A * B^T, bf16 MFMA 16x16x32, tile 128 x BN, BK=32.
// AMODE 0: A dense bf16 [p][256];  AMODE 2: A = padded h1p bf16.
// PADC: store C into padded h1p layout.
// SILU: y = acc*bias + bnB; out = y*sigmoid(y), fp32 NCHW.
// ---------------------------------------------------------------------------
template<int BN, bool GUARD, bool SILU, int AMODE, bool PADC>
__global__ __launch_bounds__(256) void k_gemm(const void* __restrict__ Asrc,
    const u16* __restrict__ Bw, const float* __restrict__ bias,
    const float* __restrict__ bnB, void* __restrict__ Cout, int ldc, int NL){
  constexpr int WN = BN / 2;
  constexpr int MF = 4;
  constexpr int NF = WN / 16;
  constexpr int BOFF = 128 * 40;
  constexpr int STG = (128 + BN) * 40;
  constexpr int CMAT = 128 * (BN + 8);
  constexpr int SM = SILU ? STG : (STG > CMAT ? STG : CMAT);
  __shared__ __align__(16) u16 smem[SM];

  const int t = threadIdx.x;
  const int tm = blockIdx.x * 128;
  const int tn = blockIdx.y * BN;
  const int lane = t & 63;
  const int wid = t >> 6;
  const int wr = wid >> 1, wc = wid & 1;

  f32x4 acc[MF][NF] = {};

  for (int kc = 0; kc < 256; kc += 32){
    if constexpr (AMODE == 2){
      const u16* Ap = (const u16*)Asrc;
      #pragma unroll
      for (int i = 0; i < 2; ++i){
        int v = t + i * 256;
        int row = v >> 2, cq = v & 3;
        int p = tm + row;
        int bb = p >> 12, ii = (p >> 6) & 63, jj = p & 63;
        size_t base = ((size_t)(bb * PIMG) + (ii + 2) * PDIM + jj + 2) * 256;
        *reinterpret_cast<u16x8*>(&smem[row * 40 + cq * 8]) =
          *reinterpret_cast<const u16x8*>(&Ap[base + kc + cq * 8]);
      }
    } else {
      const u16* Ap = (const u16*)Asrc;
      #pragma unroll
      for (int i = 0; i < 2; ++i){
        int v = t + i * 256;
        int row = v >> 2, cq = v & 3;
        *reinterpret_cast<u16x8*>(&smem[row * 40 + cq * 8]) =
          *reinterpret_cast<const u16x8*>(&Ap[(size_t)(tm + row) * 256 + kc + cq * 8]);
      }
    }
    constexpr int BV = BN * 4 / 256;
    #pragma unroll
    for (int i = 0; i < BV; ++i){
      int v = t + i * 256;
      int row = v >> 2, cq = v & 3;
      *reinterpret_cast<u16x8*>(&smem[BOFF + row * 40 + cq * 8]) =
        *reinterpret_cast<const u16x8*>(&Bw[(size_t)(tn + row) * 256 + kc + cq * 8]);
    }
    __syncthreads();
    short8 af[MF], bf[NF];
    #pragma unroll
    for (int m = 0; m < MF; ++m)
      af[m] = *reinterpret_cast<const short8*>(
        &smem[(wr * 64 + m * 16 + (lane & 15)) * 40 + (lane >> 4) * 8]);
    #pragma unroll
    for (int n = 0; n < NF; ++n)
      bf[n] = *reinterpret_cast<const short8*>(
        &smem[BOFF + (wc * WN + n * 16 + (lane & 15)) * 40 + (lane >> 4) * 8]);
    #pragma unroll
    for (int m = 0; m < MF; ++m)
      #pragma unroll
      for (int n = 0; n < NF; ++n)
        acc[m][n] = __builtin_amdgcn_mfma_f32_16x16x32_bf16(af[m], bf[n], acc[m][n], 0, 0, 0);
    __syncthreads();
  }

  if constexpr (SILU){
    const int bimg = tm >> 12;
    const int ploc = tm & 4095;
    float* outp = (float*)Cout;
    #pragma unroll
    for (int n = 0; n < NF; ++n){
      int o = tn + wc * WN + n * 16 + (lane & 15);
      float sA = bias[o], sB = bnB[o];
      #pragma unroll
      for (int m = 0; m < MF; ++m){
        int prow = wr * 64 + m * 16 + ((lane >> 4) << 2);
        f32x4 st;
        #pragma unroll
        for (int j = 0; j < 4; ++j){
          float y = acc[m][n][j] * sA + sB;
          st[j] = y / (1.f + expf(-y));
        }
        *reinterpret_cast<f32x4*>(&outp[((size_t)(bimg * 256 + o)) * HW + ploc + prow]) = st;
      }
    }
  } else {
    constexpr int CP = BN + 8;
    u16* C_l = smem;
    #pragma unroll
    for (int n = 0; n < NF; ++n){
      int col = wc * WN + n * 16 + (lane & 15);
      int o = tn + col;
      float bi = (!GUARD || o < NL) ? bias[o] : 0.f;
      #pragma unroll
      for (int m = 0; m < MF; ++m){
        int r0 = wr * 64 + m * 16 + ((lane >> 4) << 2);
        #pragma unroll
        for (int j = 0; j < 4; ++j)
          C_l[(r0 + j) * CP + col] = f2b(acc[m][n][j] + bi);
      }
    }
    __syncthreads();
    constexpr int SEG = BN / 8;
    constexpr int RPP = 256 / SEG;
    u16* Co = (u16*)Cout;
    #pragma unroll
    for (int pass = 0; pass < 128 / RPP; ++pass){
      int row = pass * RPP + t / SEG;
      int sg = t % SEG;
      int oc = tn + sg * 8;
      if constexpr (PADC){
        int p = tm + row;
        int bb = p >> 12, ii = (p >> 6) & 63, jj = p & 63;
        size_t dst = ((size_t)(bb * PIMG) + (ii + 2) * PDIM + jj + 2) * 256 + oc;
        *reinterpret_cast<u16x8*>(&Co[dst]) =
          *reinterpret_cast<const u16x8*>(&C_l[row * CP + sg * 8]);
      } else {
        if (!GUARD || oc + 8 <= NL)
          *reinterpret_cast<u16x8*>(&Co[(size_t)(tm + row) * ldc + oc]) =
            *reinterpret_cast<const u16x8*>(&C_l[row * CP + sg * 8]);
      }
    }
  }
}

// ---------------------------------------------------------------------------
// k_sample: 8 px/block, 32 lanes/px (16 groups x 2 halves), 8 ch/lane.
// Padded h1p (2-wide zero border): clamp h0,w0 to [-2,64]; h1=h0+1, w1=w0+1
// always valid -> 2 address calcs + 4 unguarded 16B loads per tap.
// ---------------------------------------------------------------------------
__global__ __launch_bounds__(256) void k_sample(const u16* __restrict__ h1p,
    const u16* __restrict__ om, u16* __restrict__ ydcn){
  __shared__ float oms[8 * MOFF];      // 13824 B
  const int t = threadIdx.x;
  const int pblk = blockIdx.x * 8;
  {
    const u16* src = om + (size_t)pblk * MOFF;
    #pragma unroll
    for (int i = 0; i < 2; ++i){
      int idx = t + i * 256;
      if (idx < 432){
        u16x8 v = *reinterpret_cast<const u16x8*>(&src[idx * 8]);
        float4 lo, hi;
        lo.x = b2f(v[0]); lo.y = b2f(v[1]); lo.z = b2f(v[2]); lo.w = b2f(v[3]);
        hi.x = b2f(v[4]); hi.y = b2f(v[5]); hi.z = b2f(v[6]); hi.w = b2f(v[7]);
        *reinterpret_cast<float4*>(&oms[idx * 8]) = lo;
        *reinterpret_cast<float4*>(&oms[idx * 8 + 4]) = hi;
      }
    }
  }
  __syncthreads();

  const int pix = t >> 5, s = t & 31;
  const int g = s >> 1, half = s & 1;
  const int p = pblk + pix;
  const int b = p >> 12, hw = p & 4095;
  const int ic = hw >> 6, jc = hw & 63;
  const u16* vb = h1p + (size_t)b * PIMG * 256 + g * 16 + half * 8;
  const float* ob = &oms[pix * MOFF + g * 27];
  const float fi = (float)ic, fj = (float)jc;

  float acc[8] = {};
  #pragma unroll
  for (int k = 0; k < 9; ++k){
    float oh = ob[2 * k], ow = ob[2 * k + 1], m = ob[18 + k];
    float ph = fi + (float)(k / 3 - 1) + oh;
    float pw = fj + (float)(k % 3 - 1) + ow;
    float h0f = floorf(ph), w0f = floorf(pw);
    float ah = ph - h0f, aw = pw - w0f;
    int h0 = (int)h0f, w0 = (int)w0f;
    int hc = min(max(h0, -2), 64) + 2;   // padded row of h0, [0,66]
    int wc = min(max(w0, -2), 64) + 2;   // padded col of w0, [0,66]
    const u16* c0 = &vb[(hc * PDIM + wc) * 256];
    const u16* c1 = c0 + PDIM * 256;
    float mh1 = m * ah, mh0 = m - mh1;
    float c01w = mh0 * aw, c00w = mh0 - c01w;
    float c11w = mh1 * aw, c10w = mh1 - c11w;
    u16x8 a00 = *reinterpret_cast<const u16x8*>(c0);
    u16x8 a01 = *reinterpret_cast<const u16x8*>(c0 + 256);
    u16x8 a10 = *reinterpret_cast<const u16x8*>(c1);
    u16x8 a11 = *reinterpret_cast<const u16x8*>(c1 + 256);
    #pragma unroll
    for (int j = 0; j < 8; ++j){
      acc[j] += c00w * b2f(a00[j]) + c01w * b2f(a01[j])
              + c10w * b2f(a10[j]) + c11w * b2f(a11[j]);
    }
  }
  u16x8 o8;
  #pragma unroll
  for (int j = 0; j < 8; ++j) o8[j] = f2b(acc[j]);
  *reinterpret_cast<u16x8*>(&ydcn[(size_t)p * 256 + g * 16 + half * 8]) = o8;
}

extern "C" void kernel_launch(void* const* d_in, const int* in_sizes, int n_in,
                              void* d_out, int out_size, void* d_ws, size_t ws_size,
                              hipStream_t stream) {
  const float* x     = (const float*)d_in[0];
  const float* w1    = (const float*)d_in[1];
  const float* b1    = (const float*)d_in[2];
  const float* woff  = (const float*)d_in[3];
  const float* boff  = (const float*)d_in[4];
  const float* w2    = (const float*)d_in[5];
  const float* gamma = (const float*)d_in[6];
  const float* beta  = (const float*)d_in[7];
  const float* mean  = (const float*)d_in[8];
  const float* var   = (const float*)d_in[9];
  float* out = (float*)d_out;
  (void)in_sizes; (void)n_in; (void)out_size; (void)ws_size;

  u16* h1p   = (u16*)d_ws;                                // 8*4624*256 u16 = 18.9 MB
  u16* om    = h1p + (size_t)8 * PIMG * 256;              // 32768*432 = 28.3 MB
  u16* xT    = om + (size_t)PTOT * MOFF;                  // 32768*256 = 16.8 MB (aliased w/ ydcn)
  u16* ydcn  = xT;
  u16* wb1   = xT + (size_t)PTOT * CCH;                   // 256*256
  u16* wboff = wb1 + 256 * 256;                           // 448*256
  u16* wb2   = wboff + 448 * 256;                         // 256*256
  float* bnA = (float*)(wb2 + 256 * 256);
  float* bnB = bnA + 256;

  dim3 blk(256);
  k_cvtw<<<dim3(1489), blk, 0, stream>>>(w1, woff, w2, gamma, beta, mean, var,
                                         wb1, wboff, wb2, bnA, bnB, h1p);
  k_xt<<<dim3(64, 4, 8), blk, 0, stream>>>(x, xT);
  k_gemm<128, false, false, 0, true><<<dim3(PTOT / 128, 2), blk, 0, stream>>>(
      (const void*)xT, wb1, b1, nullptr, (void*)h1p, 0, 256);
  k_gemm<64, true, false, 2, false><<<dim3(PTOT / 128, 7), blk, 0, stream>>>(
      (const void*)h1p, wboff, boff, nullptr, (void*)om, MOFF, MOFF);
  k_sample<<<dim3(PTOT / 8), blk, 0, stream>>>(h1p, om, ydcn);
  k_gemm<128, false, true, 0, false><<<dim3(PTOT / 128, 2), blk, 0, stream>>>(
      (const void*)ydcn, wb2, bnA, bnB, (void*)out, 0, 256);
}

// Round 5
// 104.958 us; speedup vs baseline: 1.2068x; 1.0400x over previous
//
#include <hip/hip_runtime.h>

#define HW 4096
#define CCH 256
#define MOFF 432
#define PTOT 32768
#define PDIM 68
#define PIMG (PDIM*PDIM)      // 4624 padded cells per group-plane (2-wide zero border)

typedef unsigned short u16;
typedef __attribute__((ext_vector_type(8))) short short8;
typedef __attribute__((ext_vector_type(8))) unsigned short u16x8;
typedef __attribute__((ext_vector_type(4))) unsigned short u16x4;
typedef __attribute__((ext_vector_type(4))) float f32x4;

__device__ __forceinline__ u16 f2b(float f){
  unsigned int u = __float_as_uint(f);
  unsigned int rounding = 0x7FFFu + ((u >> 16) & 1u);
  return (u16)((u + rounding) >> 16);
}
__device__ __forceinline__ float b2f(u16 s){
  return __uint_as_float(((unsigned int)s) << 16);
}

// ---------------------------------------------------------------------------
// k_cvtw: weights fp32 -> bf16, BN fold, AND zero h1p's planar borders.
// Blocks 0..960: weights/BN. Blocks 961..1488: border zero.
// h1p planar: [b*16+g][68][68][16] cells of 32B. 528 border cells/plane,
// 128 planes. Border blocks: 128 cells x 2 segs (16B) per block = 256 thr.
// ---------------------------------------------------------------------------
__global__ __launch_bounds__(256) void k_cvtw(const float* __restrict__ w1,
    const float* __restrict__ woff, const float* __restrict__ w2,
    const float* __restrict__ gamma, const float* __restrict__ beta,
    const float* __restrict__ mean, const float* __restrict__ var,
    u16* __restrict__ wb1, u16* __restrict__ wboff, u16* __restrict__ wb2,
    float* __restrict__ bnA, float* __restrict__ bnB, u16* __restrict__ h1p){
  int r = blockIdx.x, t = threadIdx.x;
  if (r < 256) wb1[r*256 + t] = f2b(w1[r*256 + t]);
  else if (r < 704){ int o = r - 256; wboff[o*256 + t] = (o < MOFF) ? f2b(woff[o*256 + t]) : (u16)0; }
  else if (r < 960){ int o = r - 704; wb2[o*256 + t] = f2b(w2[o*256 + t]); }
  else if (r == 960){
    if (t < 256){
      float sc = gamma[t] * rsqrtf(var[t] + 1e-5f);
      bnA[t] = sc;
      bnB[t] = beta[t] - mean[t] * sc;
    }
  } else {
    int n = (r - 961) * 128 + (t >> 1);   // border cell index, 0..67583
    int seg = t & 1;
    int plane = n / 528, m = n % 528;
    int row, col;
    if (m < 136){ row = m / 68; col = m % 68; }
    else if (m < 272){ int mm = m - 136; row = 66 + mm / 68; col = mm % 68; }
    else { int mm = m - 272; row = 2 + (mm >> 2); int c4 = mm & 3; col = (c4 & 1) + 66 * (c4 >> 1); }
    u16x8 z = {};
    *reinterpret_cast<u16x8*>(&h1p[((size_t)plane * PIMG + row * PDIM + col) * 16 + seg * 8]) = z;
  }
}

// ---------------------------------------------------------------------------
// k_xt: x fp32 NCHW -> xT bf16 [p][c]. Conflict-free 64x64 f32 LDS tile.
// ---------------------------------------------------------------------------
__global__ __launch_bounds__(256) void k_xt(const float* __restrict__ x,
    u16* __restrict__ xT){
  __shared__ float tile[64][65];
  const int pb = blockIdx.x * 64, cb = blockIdx.y * 64, b = blockIdx.z;
  const int t = threadIdx.x;
  const float* src = x + ((size_t)(b * CCH + cb)) * HW + pb;
  #pragma unroll
  for (int pass = 0; pass < 4; ++pass){
    int c_l = pass * 16 + (t >> 4);
    int pq = (t & 15) * 4;
    float4 v = *reinterpret_cast<const float4*>(&src[(size_t)c_l * HW + pq]);
    tile[pq + 0][c_l] = v.x; tile[pq + 1][c_l] = v.y;
    tile[pq + 2][c_l] = v.z; tile[pq + 3][c_l] = v.w;
  }
  __syncthreads();
  #pragma unroll
  for (int pass = 0; pass < 4; ++pass){
    int p_l = pass * 16 + (t >> 4);
    int cq = (t & 15) * 4;
    u16x4 o4;
    #pragma unroll
    for (int j = 0; j < 4; ++j) o4[j] = f2b(tile[p_l][cq + j]);
    *reinterpret_cast<u16x4*>(&xT[((size_t)b * HW + pb + p_l) * CCH + cb + cq]) = o4;
  }
}

// ---------------------------------------------------------------------------
// k_gemm: C[M=32768][N] = A * B^T, bf16 MFMA 16x16x32, tile 128 x BN, BK=32.
// AMODE 0: A dense bf16 [p][256];  AMODE 2: A = planar h1p bf16.
// PADC: store C into planar h1p layout.
// SILU: y = acc*bias + bnB; out = y*sigmoid(y), fp32 NCHW.
// ---------------------------------------------------------------------------
template<int BN, bool GUARD, bool SILU, int AMODE, bool PADC>
__global__ __launch_bounds__(256) void k_gemm(const void* __restrict__ Asrc,
    const u16* __restrict__ Bw, const float* __restrict__ bias,
    const float* __restrict__ bnB, void* __restrict__ Cout, int ldc, int NL){
  constexpr int WN = BN / 2;
  constexpr int MF = 4;
  constexpr int NF = WN / 16;
  constexpr int BOFF = 128 * 40;
  constexpr int STG = (128 + BN) * 40;
  constexpr int CMAT = 128 * (BN + 8);
  constexpr int SM = SILU ? STG : (STG > CMAT ? STG : CMAT);
  __shared__ __align__(16) u16 smem[SM];

  const int t = threadIdx.x;
  const int tm = blockIdx.x * 128;
  const int tn = blockIdx.y * BN;
  const int lane = t & 63;
  const int wid = t >> 6;
  const int wr = wid >> 1, wc = wid & 1;

  f32x4 acc[MF][NF] = {};

  for (int kc = 0; kc < 256; kc += 32){
    if constexpr (AMODE == 2){
      const u16* Ap = (const u16*)Asrc;
      #pragma unroll
      for (int i = 0; i < 2; ++i){
        int v = t + i * 256;
        int row = v >> 2, cq = v & 3;
        int p = tm + row;
        int bb = p >> 12, ii = (p >> 6) & 63, jj = p & 63;
        int c = kc + cq * 8;
        size_t base = ((size_t)(bb * 16 + (c >> 4)) * PIMG + (ii + 2) * PDIM + jj + 2) * 16 + (c & 15);
        *reinterpret_cast<u16x8*>(&smem[row * 40 + cq * 8]) =
          *reinterpret_cast<const u16x8*>(&Ap[base]);
      }
    } else {
      const u16* Ap = (const u16*)Asrc;
      #pragma unroll
      for (int i = 0; i < 2; ++i){
        int v = t + i * 256;
        int row = v >> 2, cq = v & 3;
        *reinterpret_cast<u16x8*>(&smem[row * 40 + cq * 8]) =
          *reinterpret_cast<const u16x8*>(&Ap[(size_t)(tm + row) * 256 + kc + cq * 8]);
      }
    }
    constexpr int BV = BN * 4 / 256;
    #pragma unroll
    for (int i = 0; i < BV; ++i){
      int v = t + i * 256;
      int row = v >> 2, cq = v & 3;
      *reinterpret_cast<u16x8*>(&smem[BOFF + row * 40 + cq * 8]) =
        *reinterpret_cast<const u16x8*>(&Bw[(size_t)(tn + row) * 256 + kc + cq * 8]);
    }
    __syncthreads();
    short8 af[MF], bf[NF];
    #pragma unroll
    for (int m = 0; m < MF; ++m)
      af[m] = *reinterpret_cast<const short8*>(
        &smem[(wr * 64 + m * 16 + (lane & 15)) * 40 + (lane >> 4) * 8]);
    #pragma unroll
    for (int n = 0; n < NF; ++n)
      bf[n] = *reinterpret_cast<const short8*>(
        &smem[BOFF + (wc * WN + n * 16 + (lane & 15)) * 40 + (lane >> 4) * 8]);
    #pragma unroll
    for (int m = 0; m < MF; ++m)
      #pragma unroll
      for (int n = 0; n < NF; ++n)
        acc[m][n] = __builtin_amdgcn_mfma_f32_16x16x32_bf16(af[m], bf[n], acc[m][n], 0, 0, 0);
    __syncthreads();
  }

  if constexpr (SILU){
    const int bimg = tm >> 12;
    const int ploc = tm & 4095;
    float* outp = (float*)Cout;
    #pragma unroll
    for (int n = 0; n < NF; ++n){
      int o = tn + wc * WN + n * 16 + (lane & 15);
      float sA = bias[o], sB = bnB[o];
      #pragma unroll
      for (int m = 0; m < MF; ++m){
        int prow = wr * 64 + m * 16 + ((lane >> 4) << 2);
        f32x4 st;
        #pragma unroll
        for (int j = 0; j < 4; ++j){
          float y = acc[m][n][j] * sA + sB;
          st[j] = y / (1.f + expf(-y));
        }
        *reinterpret_cast<f32x4*>(&outp[((size_t)(bimg * 256 + o)) * HW + ploc + prow]) = st;
      }
    }
  } else {
    constexpr int CP = BN + 8;
    u16* C_l = smem;
    #pragma unroll
    for (int n = 0; n < NF; ++n){
      int col = wc * WN + n * 16 + (lane & 15);
      int o = tn + col;
      float bi = (!GUARD || o < NL) ? bias[o] : 0.f;
      #pragma unroll
      for (int m = 0; m < MF; ++m){
        int r0 = wr * 64 + m * 16 + ((lane >> 4) << 2);
        #pragma unroll
        for (int j = 0; j < 4; ++j)
          C_l[(r0 + j) * CP + col] = f2b(acc[m][n][j] + bi);
      }
    }
    __syncthreads();
    constexpr int SEG = BN / 8;
    constexpr int RPP = 256 / SEG;
    u16* Co = (u16*)Cout;
    #pragma unroll
    for (int pass = 0; pass < 128 / RPP; ++pass){
      int row = pass * RPP + t / SEG;
      int sg = t % SEG;
      int oc = tn + sg * 8;
      if constexpr (PADC){
        int p = tm + row;
        int bb = p >> 12, ii = (p >> 6) & 63, jj = p & 63;
        size_t dst = ((size_t)(bb * 16 + (oc >> 4)) * PIMG + (ii + 2) * PDIM + jj + 2) * 16 + (oc & 15);
        *reinterpret_cast<u16x8*>(&Co[dst]) =
          *reinterpret_cast<const u16x8*>(&C_l[row * CP + sg * 8]);
      } else {
        if (!GUARD || oc + 8 <= NL)
          *reinterpret_cast<u16x8*>(&Co[(size_t)(tm + row) * ldc + oc]) =
            *reinterpret_cast<const u16x8*>(&C_l[row * CP + sg * 8]);
      }
    }
  }
}

// ---------------------------------------------------------------------------
// k_sample: planar h1p, 4 px/block (1 px per wave), 4-lane units per group.
// Unit (px,g): top corner-row (w0,w0+1) = one contiguous 64B span -> the
// unit's 4 lanes cover it with ONE u16x8 load each; bottom row likewise.
// Lane q: w-corner q>>1, channel half q&1. Pair-reduce via shfl_xor(2).
// ---------------------------------------------------------------------------
__global__ __launch_bounds__(256) void k_sample(const u16* __restrict__ h1p,
    const u16* __restrict__ om, u16* __restrict__ ydcn){
  __shared__ float oms[4 * MOFF];      // 6912 B
  const int t = threadIdx.x;
  const int pblk = blockIdx.x * 4;
  if (t < 216){
    u16x8 v = *reinterpret_cast<const u16x8*>(&om[(size_t)pblk * MOFF + t * 8]);
    float4 lo, hi;
    lo.x = b2f(v[0]); lo.y = b2f(v[1]); lo.z = b2f(v[2]); lo.w = b2f(v[3]);
    hi.x = b2f(v[4]); hi.y = b2f(v[5]); hi.z = b2f(v[6]); hi.w = b2f(v[7]);
    *reinterpret_cast<float4*>(&oms[t * 8]) = lo;
    *reinterpret_cast<float4*>(&oms[t * 8 + 4]) = hi;
  }
  __syncthreads();

  const int px = t >> 6;               // wave id = pixel
  const int g = (t >> 2) & 15;
  const int q = t & 3;
  const int p = pblk + px;
  const int b = p >> 12, hw = p & 4095;
  const int ic = hw >> 6, jc = hw & 63;
  const u16* plane = h1p + (size_t)(b * 16 + g) * PIMG * 16;
  const float* ob = &oms[px * MOFF + g * 27];
  const float fi = (float)ic, fj = (float)jc;
  const bool wsel = (q >= 2);

  float acc[8] = {};
  #pragma unroll
  for (int k = 0; k < 9; ++k){
    float oh = ob[2 * k], ow = ob[2 * k + 1], m = ob[18 + k];
    float ph = fi + (float)(k / 3 - 1) + oh;
    float pw = fj + (float)(k % 3 - 1) + ow;
    float h0f = floorf(ph), w0f = floorf(pw);
    float ah = ph - h0f, aw = pw - w0f;
    int h0 = (int)h0f, w0 = (int)w0f;
    int hc = min(max(h0, -2), 64) + 2;    // [0,66]
    int wc = min(max(w0, -2), 64) + 2;    // [0,66]
    const u16* cbase = plane + ((hc * PDIM + wc) << 4) + (q << 3);
    u16x8 tv = *reinterpret_cast<const u16x8*>(cbase);
    u16x8 bv = *reinterpret_cast<const u16x8*>(cbase + PDIM * 16);
    float mh1 = m * ah, mh0 = m - mh1;
    float awq = wsel ? aw : (1.f - aw);
    float ct = mh0 * awq, cb = mh1 * awq;
    #pragma unroll
    for (int j = 0; j < 8; ++j)
      acc[j] += ct * b2f(tv[j]) + cb * b2f(bv[j]);
  }
  #pragma unroll
  for (int j = 0; j < 8; ++j)
    acc[j] += __shfl_xor(acc[j], 2, 64);
  if (q < 2){
    u16x8 o8;
    #pragma unroll
    for (int j = 0; j < 8; ++j) o8[j] = f2b(acc[j]);
    *reinterpret_cast<u16x8*>(&ydcn[(size_t)p * 256 + g * 16 + q * 8]) = o8;
  }
}

extern "C" void kernel_launch(void* const* d_in, const int* in_sizes, int n_in,
                              void* d_out, int out_size, void* d_ws, size_t ws_size,
                              hipStream_t stream) {
  const float* x     = (const float*)d_in[0];
  const float* w1    = (const float*)d_in[1];
  const float* b1    = (const float*)d_in[2];
  const float* woff  = (const float*)d_in[3];
  const float* boff  = (const float*)d_in[4];
  const float* w2    = (const float*)d_in[5];
  const float* gamma = (const float*)d_in[6];
  const float* beta  = (const float*)d_in[7];
  const float* mean  = (const float*)d_in[8];
  const float* var   = (const float*)d_in[9];
  float* out = (float*)d_out;
  (void)in_sizes; (void)n_in; (void)out_size; (void)ws_size;

  u16* h1p   = (u16*)d_ws;                                // 128 planes * 4624 * 32B = 18.9 MB
  u16* om    = h1p + (size_t)128 * PIMG * 16;             // 32768*432 = 28.3 MB
  u16* xT    = om + (size_t)PTOT * MOFF;                  // 32768*256 = 16.8 MB (aliased w/ ydcn)
  u16* ydcn  = xT;
  u16* wb1   = xT + (size_t)PTOT * CCH;                   // 256*256
  u16* wboff = wb1 + 256 * 256;                           // 448*256
  u16* wb2   = wboff + 448 * 256;                         // 256*256
  float* bnA = (float*)(wb2 + 256 * 256);
  float* bnB = bnA + 256;

  dim3 blk(256);
  k_cvtw<<<dim3(1489), blk, 0, stream>>>(w1, woff, w2, gamma, beta, mean, var,
                                         wb1, wboff, wb2, bnA, bnB, h1p);
  k_xt<<<dim3(64, 4, 8), blk, 0, stream>>>(x, xT);
  k_gemm<128, false, false, 0, true><<<dim3(PTOT / 128, 2), blk, 0, stream>>>(
      (const void*)xT, wb1, b1, nullptr, (void*)h1p, 0, 256);
  k_gemm<64, true, false, 2, false><<<dim3(PTOT / 128, 7), blk, 0, stream>>>(
      (const void*)h1p, wboff, boff, nullptr, (void*)om, MOFF, MOFF);
  k_sample<<<dim3(PTOT / 4), blk, 0, stream>>>(h1p, om, ydcn);
  k_gemm<128, false, true, 0, false><<<dim3(PTOT / 128, 2), blk, 0, stream>>>(
      (const void*)ydcn, wb2, bnA, bnB, (void*)out, 0, 256);
}

// Round 6
// 104.412 us; speedup vs baseline: 1.2131x; 1.0052x over previous
//
#include <hip/hip_runtime.h>

#define HW 4096
#define CCH 256
#define MOFF 432
#define PTOT 32768
#define PDIM 68
#define PIMG (PDIM*PDIM)      // 4624 padded cells per group-plane (2-wide zero border)

typedef unsigned short u16;
typedef __attribute__((ext_vector_type(8))) short short8;
typedef __attribute__((ext_vector_type(8))) unsigned short u16x8;
typedef __attribute__((ext_vector_type(4))) unsigned short u16x4;
typedef __attribute__((ext_vector_type(4))) float f32x4;

__device__ __forceinline__ u16 f2b(float f){
  unsigned int u = __float_as_uint(f);
  unsigned int rounding = 0x7FFFu + ((u >> 16) & 1u);
  return (u16)((u + rounding) >> 16);
}
__device__ __forceinline__ float b2f(u16 s){
  return __uint_as_float(((unsigned int)s) << 16);
}

// ---------------------------------------------------------------------------
// k_cvtw: wb_big rows 0-255 = bf16(w1); rows 688-767 = 0; wb2 = bf16(w2);
// BN fold; zero h1p planar borders.
// grid 1121: [0,256) w1 | [256,336) zero-pad | [336,592) w2 | 592 BN |
//            [593,1121) border zero (128 cells x 2 segs per block).
// ---------------------------------------------------------------------------
__global__ __launch_bounds__(256) void k_cvtw(const float* __restrict__ w1,
    const float* __restrict__ w2,
    const float* __restrict__ gamma, const float* __restrict__ beta,
    const float* __restrict__ mean, const float* __restrict__ var,
    u16* __restrict__ wb_big, u16* __restrict__ wb2,
    float* __restrict__ bnA, float* __restrict__ bnB, u16* __restrict__ h1p){
  int r = blockIdx.x, t = threadIdx.x;
  if (r < 256) wb_big[r*256 + t] = f2b(w1[r*256 + t]);
  else if (r < 336){ wb_big[(688 + (r - 256)) * 256 / 1 + t] = 0; }  // zero pad rows 688..767... (see below)
  else if (r < 592){ int o = r - 336; wb2[o*256 + t] = f2b(w2[o*256 + t]); }
  else if (r == 592){
    if (t < 256){
      float sc = gamma[t] * rsqrtf(var[t] + 1e-5f);
      bnA[t] = sc;
      bnB[t] = beta[t] - mean[t] * sc;
    }
  } else {
    int n = (r - 593) * 128 + (t >> 1);   // border cell index, 0..67583
    int seg = t & 1;
    int plane = n / 528, m = n % 528;
    int row, col;
    if (m < 136){ row = m / 68; col = m % 68; }
    else if (m < 272){ int mm = m - 136; row = 66 + mm / 68; col = mm % 68; }
    else { int mm = m - 272; row = 2 + (mm >> 2); int c4 = mm & 3; col = (c4 & 1) + 66 * (c4 >> 1); }
    u16x8 z = {};
    *reinterpret_cast<u16x8*>(&h1p[((size_t)plane * PIMG + row * PDIM + col) * 16 + seg * 8]) = z;
  }
}

// ---------------------------------------------------------------------------
// k_wcomb: wcomb[j] = woff[j] . w1  (row j of combined weight, fp32 acc),
// stored as wb_big rows 256..687 (bf16). bcomb[j] = woff[j].b1 + boff[j].
// grid 432 x 256.
// ---------------------------------------------------------------------------
__global__ __launch_bounds__(256) void k_wcomb(const float* __restrict__ w1,
    const float* __restrict__ woff, const float* __restrict__ b1,
    const float* __restrict__ boff,
    u16* __restrict__ wb_big, float* __restrict__ bcomb){
  __shared__ float wr_[256];
  __shared__ float pb[256];
  const int j = blockIdx.x, t = threadIdx.x;
  wr_[t] = woff[j * 256 + t];
  __syncthreads();
  float s = 0.f;
  #pragma unroll 8
  for (int m = 0; m < 256; ++m) s += wr_[m] * w1[m * 256 + t];
  wb_big[(256 + j) * 256 + t] = f2b(s);
  pb[t] = wr_[t] * b1[t];
  __syncthreads();
  if (t == 0){
    float bs = boff[j];
    for (int m = 0; m < 256; ++m) bs += pb[m];
    bcomb[j] = bs;
  }
}

// ---------------------------------------------------------------------------
// k_xt: x fp32 NCHW -> xT bf16 [p][c]. Conflict-free 64x64 f32 LDS tile.
// ---------------------------------------------------------------------------
__global__ __launch_bounds__(256) void k_xt(const float* __restrict__ x,
    u16* __restrict__ xT){
  __shared__ float tile[64][65];
  const int pb = blockIdx.x * 64, cb = blockIdx.y * 64, b = blockIdx.z;
  const int t = threadIdx.x;
  const float* src = x + ((size_t)(b * CCH + cb)) * HW + pb;
  #pragma unroll
  for (int pass = 0; pass < 4; ++pass){
    int c_l = pass * 16 + (t >> 4);
    int pq = (t & 15) * 4;
    float4 v = *reinterpret_cast<const float4*>(&src[(size_t)c_l * HW + pq]);
    tile[pq + 0][c_l] = v.x; tile[pq + 1][c_l] = v.y;
    tile[pq + 2][c_l] = v.z; tile[pq + 3][c_l] = v.w;
  }
  __syncthreads();
  #pragma unroll
  for (int pass = 0; pass < 4; ++pass){
    int p_l = pass * 16 + (t >> 4);
    int cq = (t & 15) * 4;
    u16x4 o4;
    #pragma unroll
    for (int j = 0; j < 4; ++j) o4[j] = f2b(tile[p_l][cq + j]);
    *reinterpret_cast<u16x4*>(&xT[((size_t)b * HW + pb + p_l) * CCH + cb + cq]) = o4;
  }
}

// ---------------------------------------------------------------------------
// k_gemm_big: [h1 | om] = xT * wb_big^T, tile 128x128, K=256, MFMA 16x16x32.
// 1D grid 1536 with XCD swizzle: the 6 col-blocks of a row-stripe run
// consecutively on one XCD (xT stripe stays L2-hot).
// cols 0-255 -> h1p planar (+b1); cols 256-687 -> om (+bcomb), guard 432.
// ---------------------------------------------------------------------------
__global__ __launch_bounds__(256) void k_gemm_big(const u16* __restrict__ A,
    const u16* __restrict__ Bw, const float* __restrict__ b1,
    const float* __restrict__ bcomb, u16* __restrict__ h1p,
    u16* __restrict__ om){
  __shared__ __align__(16) u16 smem[128 * 136];   // epilogue needs 128*(128+8)
  const int bid = blockIdx.x;
  const int xcd = bid & 7, s = bid >> 3;
  const int row_local = s / 6, cblk = s % 6;
  const int tm = (row_local * 8 + xcd) * 128;
  const int tn = cblk * 128;

  const int t = threadIdx.x;
  const int lane = t & 63;
  const int wid = t >> 6;
  const int wr = wid >> 1, wc = wid & 1;
  constexpr int BOFF = 128 * 40;

  f32x4 acc[4][4] = {};

  for (int kc = 0; kc < 256; kc += 32){
    #pragma unroll
    for (int i = 0; i < 2; ++i){
      int v = t + i * 256;
      int row = v >> 2, cq = v & 3;
      *reinterpret_cast<u16x8*>(&smem[row * 40 + cq * 8]) =
        *reinterpret_cast<const u16x8*>(&A[(size_t)(tm + row) * 256 + kc + cq * 8]);
    }
    #pragma unroll
    for (int i = 0; i < 2; ++i){
      int v = t + i * 256;
      int row = v >> 2, cq = v & 3;
      *reinterpret_cast<u16x8*>(&smem[BOFF + row * 40 + cq * 8]) =
        *reinterpret_cast<const u16x8*>(&Bw[(size_t)(tn + row) * 256 + kc + cq * 8]);
    }
    __syncthreads();
    short8 af[4], bf[4];
    #pragma unroll
    for (int m = 0; m < 4; ++m)
      af[m] = *reinterpret_cast<const short8*>(
        &smem[(wr * 64 + m * 16 + (lane & 15)) * 40 + (lane >> 4) * 8]);
    #pragma unroll
    for (int n = 0; n < 4; ++n)
      bf[n] = *reinterpret_cast<const short8*>(
        &smem[BOFF + (wc * 64 + n * 16 + (lane & 15)) * 40 + (lane >> 4) * 8]);
    #pragma unroll
    for (int m = 0; m < 4; ++m)
      #pragma unroll
      for (int n = 0; n < 4; ++n)
        acc[m][n] = __builtin_amdgcn_mfma_f32_16x16x32_bf16(af[m], bf[n], acc[m][n], 0, 0, 0);
    __syncthreads();
  }

  constexpr int CP = 136;
  u16* C_l = smem;
  #pragma unroll
  for (int n = 0; n < 4; ++n){
    int col = wc * 64 + n * 16 + (lane & 15);
    int o = tn + col;
    float bi = (o < 256) ? b1[o] : ((o - 256 < MOFF) ? bcomb[o - 256] : 0.f);
    #pragma unroll
    for (int m = 0; m < 4; ++m){
      int r0 = wr * 64 + m * 16 + ((lane >> 4) << 2);
      #pragma unroll
      for (int j = 0; j < 4; ++j)
        C_l[(r0 + j) * CP + col] = f2b(acc[m][n][j] + bi);
    }
  }
  __syncthreads();
  // 16 vec8 segments per row, 16 rows per pass, 8 passes
  #pragma unroll
  for (int pass = 0; pass < 8; ++pass){
    int row = pass * 16 + (t >> 4);
    int sg = t & 15;
    int oc = tn + sg * 8;
    int p = tm + row;
    if (tn < 256){
      int bb = p >> 12, ii = (p >> 6) & 63, jj = p & 63;
      size_t dst = ((size_t)(bb * 16 + (oc >> 4)) * PIMG + (ii + 2) * PDIM + jj + 2) * 16 + (oc & 15);
      *reinterpret_cast<u16x8*>(&h1p[dst]) =
        *reinterpret_cast<const u16x8*>(&C_l[row * CP + sg * 8]);
    } else {
      int occ = oc - 256;
      if (occ + 8 <= MOFF)
        *reinterpret_cast<u16x8*>(&om[(size_t)p * MOFF + occ]) =
          *reinterpret_cast<const u16x8*>(&C_l[row * CP + sg * 8]);
    }
  }
}

// ---------------------------------------------------------------------------
// k_gemm2: conv2 + BN + SiLU, tile 128x128, out fp32 NCHW.
// ---------------------------------------------------------------------------
__global__ __launch_bounds__(256) void k_gemm2(const u16* __restrict__ A,
    const u16* __restrict__ Bw, const float* __restrict__ bnA,
    const float* __restrict__ bnB, float* __restrict__ out){
  __shared__ __align__(16) u16 smem[(128 + 128) * 40];
  const int t = threadIdx.x;
  const int tm = blockIdx.x * 128;
  const int tn = blockIdx.y * 128;
  const int lane = t & 63;
  const int wid = t >> 6;
  const int wr = wid >> 1, wc = wid & 1;
  constexpr int BOFF = 128 * 40;

  f32x4 acc[4][4] = {};

  for (int kc = 0; kc < 256; kc += 32){
    #pragma unroll
    for (int i = 0; i < 2; ++i){
      int v = t + i * 256;
      int row = v >> 2, cq = v & 3;
      *reinterpret_cast<u16x8*>(&smem[row * 40 + cq * 8]) =
        *reinterpret_cast<const u16x8*>(&A[(size_t)(tm + row) * 256 + kc + cq * 8]);
    }
    #pragma unroll
    for (int i = 0; i < 2; ++i){
      int v = t + i * 256;
      int row = v >> 2, cq = v & 3;
      *reinterpret_cast<u16x8*>(&smem[BOFF + row * 40 + cq * 8]) =
        *reinterpret_cast<const u16x8*>(&Bw[(size_t)(tn + row) * 256 + kc + cq * 8]);
    }
    __syncthreads();
    short8 af[4], bf[4];
    #pragma unroll
    for (int m = 0; m < 4; ++m)
      af[m] = *reinterpret_cast<const short8*>(
        &smem[(wr * 64 + m * 16 + (lane & 15)) * 40 + (lane >> 4) * 8]);
    #pragma unroll
    for (int n = 0; n < 4; ++n)
      bf[n] = *reinterpret_cast<const short8*>(
        &smem[BOFF + (wc * 64 + n * 16 + (lane & 15)) * 40 + (lane >> 4) * 8]);
    #pragma unroll
    for (int m = 0; m < 4; ++m)
      #pragma unroll
      for (int n = 0; n < 4; ++n)
        acc[m][n] = __builtin_amdgcn_mfma_f32_16x16x32_bf16(af[m], bf[n], acc[m][n], 0, 0, 0);
    __syncthreads();
  }

  const int bimg = tm >> 12;
  const int ploc = tm & 4095;
  #pragma unroll
  for (int n = 0; n < 4; ++n){
    int o = tn + wc * 64 + n * 16 + (lane & 15);
    float sA = bnA[o], sB = bnB[o];
    #pragma unroll
    for (int m = 0; m < 4; ++m){
      int prow = wr * 64 + m * 16 + ((lane >> 4) << 2);
      f32x4 st;
      #pragma unroll
      for (int j = 0; j < 4; ++j){
        float y = acc[m][n][j] * sA + sB;
        st[j] = y / (1.f + expf(-y));
      }
      *reinterpret_cast<f32x4*>(&out[((size_t)(bimg * 256 + o)) * HW + ploc + prow]) = st;
    }
  }
}

// ---------------------------------------------------------------------------
// k_sample: planar h1p, 4 px/block (1 px per wave), 4-lane units per group.
// ---------------------------------------------------------------------------
__global__ __launch_bounds__(256) void k_sample(const u16* __restrict__ h1p,
    const u16* __restrict__ om, u16* __restrict__ ydcn){
  __shared__ float oms[4 * MOFF];      // 6912 B
  const int t = threadIdx.x;
  const int pblk = blockIdx.x * 4;
  if (t < 216){
    u16x8 v = *reinterpret_cast<const u16x8*>(&om[(size_t)pblk * MOFF + t * 8]);
    float4 lo, hi;
    lo.x = b2f(v[0]); lo.y = b2f(v[1]); lo.z = b2f(v[2]); lo.w = b2f(v[3]);
    hi.x = b2f(v[4]); hi.y = b2f(v[5]); hi.z = b2f(v[6]); hi.w = b2f(v[7]);
    *reinterpret_cast<float4*>(&oms[t * 8]) = lo;
    *reinterpret_cast<float4*>(&oms[t * 8 + 4]) = hi;
  }
  __syncthreads();

  const int px = t >> 6;
  const int g = (t >> 2) & 15;
  const int q = t & 3;
  const int p = pblk + px;
  const int b = p >> 12, hw = p & 4095;
  const int ic = hw >> 6, jc = hw & 63;
  const u16* plane = h1p + (size_t)(b * 16 + g) * PIMG * 16;
  const float* ob = &oms[px * MOFF + g * 27];
  const float fi = (float)ic, fj = (float)jc;
  const bool wsel = (q >= 2);

  float acc[8] = {};
  #pragma unroll
  for (int k = 0; k < 9; ++k){
    float oh = ob[2 * k], ow = ob[2 * k + 1], m = ob[18 + k];
    float ph = fi + (float)(k / 3 - 1) + oh;
    float pw = fj + (float)(k % 3 - 1) + ow;
    float h0f = floorf(ph), w0f = floorf(pw);
    float ah = ph - h0f, aw = pw - w0f;
    int h0 = (int)h0f, w0 = (int)w0f;
    int hc = min(max(h0, -2), 64) + 2;
    int wc = min(max(w0, -2), 64) + 2;
    const u16* cbase = plane + ((hc * PDIM + wc) << 4) + (q << 3);
    u16x8 tv = *reinterpret_cast<const u16x8*>(cbase);
    u16x8 bv = *reinterpret_cast<const u16x8*>(cbase + PDIM * 16);
    float mh1 = m * ah, mh0 = m - mh1;
    float awq = wsel ? aw : (1.f - aw);
    float ct = mh0 * awq, cb = mh1 * awq;
    #pragma unroll
    for (int j = 0; j < 8; ++j)
      acc[j] += ct * b2f(tv[j]) + cb * b2f(bv[j]);
  }
  #pragma unroll
  for (int j = 0; j < 8; ++j)
    acc[j] += __shfl_xor(acc[j], 2, 64);
  if (q < 2){
    u16x8 o8;
    #pragma unroll
    for (int j = 0; j < 8; ++j) o8[j] = f2b(acc[j]);
    *reinterpret_cast<u16x8*>(&ydcn[(size_t)p * 256 + g * 16 + q * 8]) = o8;
  }
}

extern "C" void kernel_launch(void* const* d_in, const int* in_sizes, int n_in,
                              void* d_out, int out_size, void* d_ws, size_t ws_size,
                              hipStream_t stream) {
  const float* x     = (const float*)d_in[0];
  const float* w1    = (const float*)d_in[1];
  const float* b1    = (const float*)d_in[2];
  const float* woff  = (const float*)d_in[3];
  const float* boff  = (const float*)d_in[4];
  const float* w2    = (const float*)d_in[5];
  const float* gamma = (const float*)d_in[6];
  const float* beta  = (const float*)d_in[7];
  const float* mean  = (const float*)d_in[8];
  const float* var   = (const float*)d_in[9];
  float* out = (float*)d_out;
  (void)in_sizes; (void)n_in; (void)out_size; (void)ws_size;

  u16* h1p    = (u16*)d_ws;                               // 128 planes * 4624 * 32B = 18.9 MB
  u16* om     = h1p + (size_t)128 * PIMG * 16;            // 32768*432 = 28.3 MB
  u16* xT     = om + (size_t)PTOT * MOFF;                 // 32768*256 = 16.8 MB (aliased w/ ydcn)
  u16* ydcn   = xT;
  u16* wb_big = xT + (size_t)PTOT * CCH;                  // 768*256 bf16
  u16* wb2    = wb_big + 768 * 256;                       // 256*256
  float* bnA  = (float*)(wb2 + 256 * 256);
  float* bnB  = bnA + 256;
  float* bcomb = bnB + 256;                               // 432 f32

  dim3 blk(256);
  k_cvtw<<<dim3(1121), blk, 0, stream>>>(w1, w2, gamma, beta, mean, var,
                                         wb_big, wb2, bnA, bnB, h1p);
  k_wcomb<<<dim3(432), blk, 0, stream>>>(w1, woff, b1, boff, wb_big, bcomb);
  k_xt<<<dim3(64, 4, 8), blk, 0, stream>>>(x, xT);
  k_gemm_big<<<dim3(1536), blk, 0, stream>>>(xT, wb_big, b1, bcomb, h1p, om);
  k_sample<<<dim3(PTOT / 4), blk, 0, stream>>>(h1p, om, ydcn);
  k_gemm2<<<dim3(PTOT / 128, 2), blk, 0, stream>>>(ydcn, wb2, bnA, bnB, out);
}